// Round 6
// baseline (940.983 us; speedup 1.0000x reference)
//
#include <hip/hip_runtime.h>
#include <hip/hip_bf16.h>
#include <math.h>

#define C_DIM 1024
#define H_DIM 4096
#define E_NUM 8

typedef __bf16 bf16x8 __attribute__((ext_vector_type(8)));
typedef float f32x4 __attribute__((ext_vector_type(4)));

__device__ __forceinline__ unsigned short f2bf(float f) {
  union { float f; unsigned u; } v; v.f = f;
  unsigned r = v.u + 0x7FFFu + ((v.u >> 16) & 1u);   // round-to-nearest-even
  return (unsigned short)(r >> 16);
}

__device__ __forceinline__ void gload16(const short* g, short* l) {
  __builtin_amdgcn_global_load_lds(
      (const __attribute__((address_space(1))) unsigned int*)g,
      (__attribute__((address_space(3))) unsigned int*)l, 16, 0, 0);
}

// ---------------------------------------------------------------------------
// Router (validated rounds 1-5)
// ---------------------------------------------------------------------------
__global__ __launch_bounds__(256) void router_kernel(
    const float* __restrict__ x, const float* __restrict__ noise,
    const float* __restrict__ Wr, const float* __restrict__ Wn,
    int2* __restrict__ idx_out, float2* __restrict__ gate_out, int N)
{
  int t = blockIdx.x;
  int tid = threadIdx.x;
  const float* xrow = x + (size_t)t * C_DIM;
  float accR[E_NUM], accN[E_NUM];
#pragma unroll
  for (int e = 0; e < E_NUM; e++) { accR[e] = 0.f; accN[e] = 0.f; }
  for (int c = tid; c < C_DIM; c += 256) {
    float xv = xrow[c];
    const float* wr = Wr + (size_t)c * E_NUM;
    const float* wn = Wn + (size_t)c * E_NUM;
#pragma unroll
    for (int e = 0; e < E_NUM; e++) {
      accR[e] = fmaf(xv, wr[e], accR[e]);
      accN[e] = fmaf(xv, wn[e], accN[e]);
    }
  }
#pragma unroll
  for (int e = 0; e < E_NUM; e++) {
    for (int off = 32; off > 0; off >>= 1) {
      accR[e] += __shfl_down(accR[e], off, 64);
      accN[e] += __shfl_down(accN[e], off, 64);
    }
  }
  __shared__ float red[4][2 * E_NUM];
  int lane = tid & 63, wave = tid >> 6;
  if (lane == 0) {
#pragma unroll
    for (int e = 0; e < E_NUM; e++) { red[wave][e] = accR[e]; red[wave][E_NUM + e] = accN[e]; }
  }
  __syncthreads();
  if (tid == 0) {
    float ns[E_NUM];
#pragma unroll
    for (int e = 0; e < E_NUM; e++) {
      float lg = red[0][e] + red[1][e] + red[2][e] + red[3][e];
      float nl = red[0][E_NUM + e] + red[1][E_NUM + e] + red[2][E_NUM + e] + red[3][E_NUM + e];
      float sp = fmaxf(nl, 0.f) + log1pf(expf(-fabsf(nl)));
      ns[e] = lg + noise[(size_t)t * E_NUM + e] * sp;
    }
    int i1 = 0; float m1 = ns[0];
    int i2 = -1; float m2 = -INFINITY;
#pragma unroll
    for (int e = 1; e < E_NUM; e++) {
      float v = ns[e];
      if (v > m1) { m2 = m1; i2 = i1; m1 = v; i1 = e; }
      else if (v > m2) { m2 = v; i2 = e; }
    }
    float e2 = expf(m2 - m1);
    float s = 1.f + e2;
    gate_out[t] = make_float2(1.f / s, e2 / s);
    idx_out[t] = make_int2(i1, i2);
  }
}

// ---------------------------------------------------------------------------
// Capacity scan (validated) + per-expert kept count
// ---------------------------------------------------------------------------
__global__ __launch_bounds__(256) void scan_kernel(
    const int2* __restrict__ idx, const float2* __restrict__ gates,
    int* __restrict__ s2t, float* __restrict__ gslot, int* __restrict__ counts,
    int N, int cap)
{
  int e = blockIdx.x;
  int tid = threadIdx.x;
  for (int s = tid; s < cap; s += 256) { s2t[(size_t)e * cap + s] = N; gslot[(size_t)e * cap + s] = 0.f; }
  __syncthreads();
  __shared__ int wtot[4];
  int lane = tid & 63, wave = tid >> 6;
  int running = 0;
  for (int base = 0; base < N; base += 256) {
    int t = base + tid;
    int2 ix = idx[t];
    bool flag = (ix.x == e) || (ix.y == e);
    unsigned long long m = __ballot(flag);
    int rank = __popcll(m & ((1ull << lane) - 1ull));
    if (lane == 0) wtot[wave] = __popcll(m);
    __syncthreads();
    int woff = 0;
    for (int w = 0; w < wave; w++) woff += wtot[w];
    int slot = running + woff + rank;
    if (flag && slot < cap) {
      s2t[(size_t)e * cap + slot] = t;
      gslot[(size_t)e * cap + slot] = (ix.x == e) ? gates[t].x : gates[t].y;
    }
    running += wtot[0] + wtot[1] + wtot[2] + wtot[3];
    __syncthreads();
  }
  if (tid == 0) counts[e] = min(running, cap);
}

// ---------------------------------------------------------------------------
// f32 -> bf16, 8 elems/thread (validated)
// ---------------------------------------------------------------------------
__global__ __launch_bounds__(256) void convert_x_kernel(
    const float* __restrict__ src, short* __restrict__ dst, int n8)
{
  int i = blockIdx.x * 256 + threadIdx.x;
  if (i >= n8) return;
  const float4* s = (const float4*)src + (size_t)i * 2;
  float4 a = s[0], b = s[1];
  union { unsigned short us[8]; uint4 v; } o;
  o.us[0] = f2bf(a.x); o.us[1] = f2bf(a.y); o.us[2] = f2bf(a.z); o.us[3] = f2bf(a.w);
  o.us[4] = f2bf(b.x); o.us[5] = f2bf(b.y); o.us[6] = f2bf(b.z); o.us[7] = f2bf(b.w);
  ((uint4*)dst)[i] = o.v;
}

// ---------------------------------------------------------------------------
// f32 [R][Cc] -> bf16 [Cc][R]  (validated)
// ---------------------------------------------------------------------------
__global__ __launch_bounds__(256) void transpose_convert_kernel(
    const float* __restrict__ src, short* __restrict__ dst,
    int R, int Cc)
{
  src += (size_t)blockIdx.z * R * Cc;
  dst += (size_t)blockIdx.z * (size_t)R * Cc;
  __shared__ float tile[64][65];
  int c0 = blockIdx.x * 64, r0 = blockIdx.y * 64;
  int tid = threadIdx.x;
  int tr = tid >> 4, tc = (tid & 15) * 4;
#pragma unroll
  for (int p = 0; p < 4; p++) {
    int r = p * 16 + tr;
    float4 v = *(const float4*)(src + (size_t)(r0 + r) * Cc + c0 + tc);
    tile[r][tc] = v.x; tile[r][tc + 1] = v.y; tile[r][tc + 2] = v.z; tile[r][tc + 3] = v.w;
  }
  __syncthreads();
#pragma unroll
  for (int p = 0; p < 4; p++) {
    int c = p * 16 + tr;
    union { unsigned short us[4]; ushort4 v; } o;
#pragma unroll
    for (int j = 0; j < 4; j++) o.us[j] = f2bf(tile[tc + j][c]);
    *(ushort4*)(dst + (size_t)(c0 + c) * R + r0 + tc) = o.v;
  }
}

// ---------------------------------------------------------------------------
// Simple-core MFMA GEMM (validated round 5 K-loop, unchanged): 128x128 tile,
// BK=64, 256 thr (4 waves 2x2, per-wave 64x64), double-buffered LDS 64 KB ->
// 2 blocks/CU, ONE __syncthreads per K-step, frag-reads -> stage(i+1) -> MFMA.
//
// NEW (round 6): locality-aware flat-grid decode.
//   expert = flat & 7  -> pins each expert to one XCD (dispatch round-robins
//   XCDs), so its weight panels live in ONE 4 MB L2.
//   s = flat >> 3 enumerates tiles in 8-col supergroups, row-major: the ~64
//   resident blocks/XCD form an 8x8 supertile whose A+B panels = 4 MB = L2.
// MODE 0 (mlp1): K = C_DIM; A = xbf via s2t gather; B = W1t [H][C];
//                epilogue: h = g * silu(acc) (GATE FOLDED HERE), bf16.
// MODE 1 (mlp2): split-K: kc in [0,4), K-chunk = 1024 of H_DIM; A = h [cap][H];
//                B = W2t [C][H]; epilogue: atomicAdd into out (no gate).
// ---------------------------------------------------------------------------
template<int MODE>
__global__ __launch_bounds__(256, 2) void gemm_moe(
    const short* __restrict__ Abase, const short* __restrict__ Wt,
    const int* __restrict__ s2t, const float* __restrict__ gslot,
    const int* __restrict__ counts, void* __restrict__ outp,
    int cap, int N, int rows)
{
  __shared__ short As[2][8192];   // [buf][kb*1024 + row*8]
  __shared__ short Bs[2][8192];

  // locality decode: e -> XCD, s -> supertile order within expert
  int flat = blockIdx.x;
  int e = flat & 7;
  int s = flat >> 3;
  int perGrp = rows * 8;          // tiles per 8-col supergroup
  int grp = s / perGrp;
  int loc = s - grp * perGrp;
  int r = loc >> 3;
  int c, kc;
  if (MODE == 0) { c = grp * 8 + (loc & 7); kc = 0; }
  else           { c = loc & 7;             kc = grp; }

  int cnt = counts[e];
  int row0 = r * 128;
  if (row0 >= cnt) return;        // whole block is pad slots
  int col0 = c * 128;

  int tid = threadIdx.x;
  int w = tid >> 6, l = tid & 63;
  int wr = w >> 1, wc = w & 1;
  int rowT = tid & 127, kbT = tid >> 7;   // staging: row + kb-parity

  const int NS = 16;              // K-chunk 1024 both modes, BK=64

  const short *pA, *pB;
  if (MODE == 0) {
    int tok = min(s2t[(size_t)e * cap + row0 + rowT], N - 1);  // pad: harmless gather
    pA = Abase + (size_t)tok * C_DIM;
    pB = Wt + (size_t)e * (C_DIM * H_DIM) + (size_t)(col0 + rowT) * C_DIM;
  } else {
    pA = Abase + ((size_t)e * cap + row0 + rowT) * H_DIM + kc * 1024;
    pB = Wt + (size_t)e * (C_DIM * H_DIM) + (size_t)(col0 + rowT) * H_DIM + kc * 1024;
  }

  // frag read bases (shorts): [kb = kk*4 + (l>>4)][row = w*64 + m*16 + (l&15)]
  int aBase = (l >> 4) * 1024 + (wr * 64 + (l & 15)) * 8;
  int bBase = (l >> 4) * 1024 + (wc * 64 + (l & 15)) * 8;

  f32x4 acc[4][4];
#pragma unroll
  for (int m = 0; m < 4; m++)
#pragma unroll
    for (int n = 0; n < 4; n++) acc[m][n] = 0.f;

#define STAGE(k0, buf) { \
  _Pragma("unroll") for (int j = 0; j < 4; ++j) { \
    int kb = kbT + 2 * j; \
    gload16(pA + (k0) + kb * 8, &As[buf][kb * 1024 + rowT * 8]); \
    gload16(pB + (k0) + kb * 8, &Bs[buf][kb * 1024 + rowT * 8]); \
  } }

  STAGE(0, 0);
  int cur = 0;
#pragma unroll 1
  for (int i = 0; i < NS; ++i) {
    __syncthreads();              // compiler adds vmcnt(0): buf[cur] ready
    bf16x8 af[4][2], bg[4][2];
#pragma unroll
    for (int m = 0; m < 4; m++)
#pragma unroll
      for (int kk = 0; kk < 2; kk++)
        af[m][kk] = *(const bf16x8*)&As[cur][aBase + m * 128 + kk * 4096];
#pragma unroll
    for (int n = 0; n < 4; n++)
#pragma unroll
      for (int kk = 0; kk < 2; kk++)
        bg[n][kk] = *(const bf16x8*)&Bs[cur][bBase + n * 128 + kk * 4096];
    if (i + 1 < NS) STAGE((i + 1) * 64, cur ^ 1);
#pragma unroll
    for (int m = 0; m < 4; m++)
#pragma unroll
      for (int n = 0; n < 4; n++) {
        acc[m][n] = __builtin_amdgcn_mfma_f32_16x16x32_bf16(af[m][0], bg[n][0], acc[m][n], 0, 0, 0);
        acc[m][n] = __builtin_amdgcn_mfma_f32_16x16x32_bf16(af[m][1], bg[n][1], acc[m][n], 0, 0, 0);
      }
    cur ^= 1;
  }
#undef STAGE

  // ---- epilogue (validated round-2 C/D mapping) ----
  int orow = row0 + wr * 64 + (l >> 4) * 4;
  int ocol = col0 + wc * 64 + (l & 15);
  if (MODE == 0) {
    short* hE = (short*)outp + (size_t)e * cap * H_DIM;
#pragma unroll
    for (int m = 0; m < 4; m++)
#pragma unroll
      for (int rr = 0; rr < 4; rr++) {
        int slot = orow + m * 16 + rr;
        float g = gslot[(size_t)e * cap + slot];   // 0 for pad slots -> h = 0
        size_t rb = (size_t)slot * H_DIM + ocol;
#pragma unroll
        for (int n = 0; n < 4; n++) {
          float v = acc[m][n][rr];
          hE[rb + n * 16] = (short)f2bf(g * (v / (1.f + expf(-v))));
        }
      }
  } else {
    float* out = (float*)outp;
#pragma unroll
    for (int m = 0; m < 4; m++)
#pragma unroll
      for (int rr = 0; rr < 4; rr++) {
        int slot = orow + m * 16 + rr;
        int tok = s2t[(size_t)e * cap + slot];
        if (tok < N) {
          float* op = out + (size_t)tok * C_DIM + ocol;
#pragma unroll
          for (int n = 0; n < 4; n++)
            atomicAdd(op + n * 16, acc[m][n][rr]);
        }
      }
  }
}

extern "C" void kernel_launch(void* const* d_in, const int* in_sizes, int n_in,
                              void* d_out, int out_size, void* d_ws, size_t ws_size,
                              hipStream_t stream)
{
  const float* x     = (const float*)d_in[0];
  const float* noise = (const float*)d_in[1];
  const float* Wr    = (const float*)d_in[2];
  const float* Wn    = (const float*)d_in[3];
  const float* W1    = (const float*)d_in[4];
  const float* W2    = (const float*)d_in[5];
  float* out = (float*)d_out;

  int N = in_sizes[0] / C_DIM;                        // 8192
  int cap = (int)((double)N * 2.0 / E_NUM * 1.25);    // 2560
  int rows = cap / 128;                               // 20

  size_t off = 0;
  auto alloc = [&](size_t bytes) -> char* {
    char* r = (char*)d_ws + off;
    off += (bytes + 255) & ~(size_t)255;
    return r;
  };
  int2*   idx    = (int2*)alloc((size_t)N * sizeof(int2));
  float2* gates  = (float2*)alloc((size_t)N * sizeof(float2));
  int*    s2t    = (int*)alloc((size_t)E_NUM * cap * sizeof(int));
  float*  gslot  = (float*)alloc((size_t)E_NUM * cap * sizeof(float));
  int*    counts = (int*)alloc(E_NUM * sizeof(int));
  short*  xbf    = (short*)alloc((size_t)N * C_DIM * sizeof(short));
  short*  W1t    = (short*)alloc((size_t)E_NUM * C_DIM * H_DIM * sizeof(short));
  short*  W2t    = (short*)alloc((size_t)E_NUM * C_DIM * H_DIM * sizeof(short));
  short*  h      = (short*)alloc((size_t)E_NUM * cap * H_DIM * sizeof(short));
  (void)ws_size;

  hipMemsetAsync(d_out, 0, (size_t)out_size * sizeof(float), stream);
  router_kernel<<<N, 256, 0, stream>>>(x, noise, Wr, Wn, idx, gates, N);
  scan_kernel<<<E_NUM, 256, 0, stream>>>(idx, gates, s2t, gslot, counts, N, cap);
  convert_x_kernel<<<(N * C_DIM / 8 + 255) / 256, 256, 0, stream>>>(x, xbf, N * C_DIM / 8);
  transpose_convert_kernel<<<dim3(H_DIM / 64, C_DIM / 64, E_NUM), 256, 0, stream>>>(
      W1, W1t, C_DIM, H_DIM);
  transpose_convert_kernel<<<dim3(C_DIM / 64, H_DIM / 64, E_NUM), 256, 0, stream>>>(
      W2, W2t, H_DIM, C_DIM);

  // mlp1: 8 experts x 4 col-supergroups x (rows*8) = 5120 blocks
  gemm_moe<0><<<dim3(E_NUM * (H_DIM / 128 / 8) * (rows * 8)), 256, 0, stream>>>(
      xbf, W1t, s2t, gslot, counts, h, cap, N, rows);
  // mlp2: 8 experts x 4 K-chunks x (rows*8) = 5120 blocks
  gemm_moe<1><<<dim3(E_NUM * 4 * (rows * 8)), 256, 0, stream>>>(
      h, W2t, s2t, gslot, counts, out, cap, N, rows);
}

// Round 7
// 887.068 us; speedup vs baseline: 1.0608x; 1.0608x over previous
//
#include <hip/hip_runtime.h>
#include <hip/hip_bf16.h>
#include <math.h>

#define C_DIM 1024
#define H_DIM 4096
#define E_NUM 8

typedef __bf16 bf16x8 __attribute__((ext_vector_type(8)));
typedef float f32x4 __attribute__((ext_vector_type(4)));

__device__ __forceinline__ unsigned short f2bf(float f) {
  union { float f; unsigned u; } v; v.f = f;
  unsigned r = v.u + 0x7FFFu + ((v.u >> 16) & 1u);   // round-to-nearest-even
  return (unsigned short)(r >> 16);
}

__device__ __forceinline__ void gload16(const short* g, short* l) {
  __builtin_amdgcn_global_load_lds(
      (const __attribute__((address_space(1))) unsigned int*)g,
      (__attribute__((address_space(3))) unsigned int*)l, 16, 0, 0);
}

// ---------------------------------------------------------------------------
// Router (validated rounds 1-6)
// ---------------------------------------------------------------------------
__global__ __launch_bounds__(256) void router_kernel(
    const float* __restrict__ x, const float* __restrict__ noise,
    const float* __restrict__ Wr, const float* __restrict__ Wn,
    int2* __restrict__ idx_out, float2* __restrict__ gate_out, int N)
{
  int t = blockIdx.x;
  int tid = threadIdx.x;
  const float* xrow = x + (size_t)t * C_DIM;
  float accR[E_NUM], accN[E_NUM];
#pragma unroll
  for (int e = 0; e < E_NUM; e++) { accR[e] = 0.f; accN[e] = 0.f; }
  for (int c = tid; c < C_DIM; c += 256) {
    float xv = xrow[c];
    const float* wr = Wr + (size_t)c * E_NUM;
    const float* wn = Wn + (size_t)c * E_NUM;
#pragma unroll
    for (int e = 0; e < E_NUM; e++) {
      accR[e] = fmaf(xv, wr[e], accR[e]);
      accN[e] = fmaf(xv, wn[e], accN[e]);
    }
  }
#pragma unroll
  for (int e = 0; e < E_NUM; e++) {
    for (int off = 32; off > 0; off >>= 1) {
      accR[e] += __shfl_down(accR[e], off, 64);
      accN[e] += __shfl_down(accN[e], off, 64);
    }
  }
  __shared__ float red[4][2 * E_NUM];
  int lane = tid & 63, wave = tid >> 6;
  if (lane == 0) {
#pragma unroll
    for (int e = 0; e < E_NUM; e++) { red[wave][e] = accR[e]; red[wave][E_NUM + e] = accN[e]; }
  }
  __syncthreads();
  if (tid == 0) {
    float ns[E_NUM];
#pragma unroll
    for (int e = 0; e < E_NUM; e++) {
      float lg = red[0][e] + red[1][e] + red[2][e] + red[3][e];
      float nl = red[0][E_NUM + e] + red[1][E_NUM + e] + red[2][E_NUM + e] + red[3][E_NUM + e];
      float sp = fmaxf(nl, 0.f) + log1pf(expf(-fabsf(nl)));
      ns[e] = lg + noise[(size_t)t * E_NUM + e] * sp;
    }
    int i1 = 0; float m1 = ns[0];
    int i2 = -1; float m2 = -INFINITY;
#pragma unroll
    for (int e = 1; e < E_NUM; e++) {
      float v = ns[e];
      if (v > m1) { m2 = m1; i2 = i1; m1 = v; i1 = e; }
      else if (v > m2) { m2 = v; i2 = e; }
    }
    float e2 = expf(m2 - m1);
    float s = 1.f + e2;
    gate_out[t] = make_float2(1.f / s, e2 / s);
    idx_out[t] = make_int2(i1, i2);
  }
}

// ---------------------------------------------------------------------------
// Capacity scan (validated) + per-expert kept count
// ---------------------------------------------------------------------------
__global__ __launch_bounds__(256) void scan_kernel(
    const int2* __restrict__ idx, const float2* __restrict__ gates,
    int* __restrict__ s2t, float* __restrict__ gslot, int* __restrict__ counts,
    int N, int cap)
{
  int e = blockIdx.x;
  int tid = threadIdx.x;
  for (int s = tid; s < cap; s += 256) { s2t[(size_t)e * cap + s] = N; gslot[(size_t)e * cap + s] = 0.f; }
  __syncthreads();
  __shared__ int wtot[4];
  int lane = tid & 63, wave = tid >> 6;
  int running = 0;
  for (int base = 0; base < N; base += 256) {
    int t = base + tid;
    int2 ix = idx[t];
    bool flag = (ix.x == e) || (ix.y == e);
    unsigned long long m = __ballot(flag);
    int rank = __popcll(m & ((1ull << lane) - 1ull));
    if (lane == 0) wtot[wave] = __popcll(m);
    __syncthreads();
    int woff = 0;
    for (int w = 0; w < wave; w++) woff += wtot[w];
    int slot = running + woff + rank;
    if (flag && slot < cap) {
      s2t[(size_t)e * cap + slot] = t;
      gslot[(size_t)e * cap + slot] = (ix.x == e) ? gates[t].x : gates[t].y;
    }
    running += wtot[0] + wtot[1] + wtot[2] + wtot[3];
    __syncthreads();
  }
  if (tid == 0) counts[e] = min(running, cap);
}

// ---------------------------------------------------------------------------
// f32 -> bf16, 8 elems/thread (validated)
// ---------------------------------------------------------------------------
__global__ __launch_bounds__(256) void convert_x_kernel(
    const float* __restrict__ src, short* __restrict__ dst, int n8)
{
  int i = blockIdx.x * 256 + threadIdx.x;
  if (i >= n8) return;
  const float4* s = (const float4*)src + (size_t)i * 2;
  float4 a = s[0], b = s[1];
  union { unsigned short us[8]; uint4 v; } o;
  o.us[0] = f2bf(a.x); o.us[1] = f2bf(a.y); o.us[2] = f2bf(a.z); o.us[3] = f2bf(a.w);
  o.us[4] = f2bf(b.x); o.us[5] = f2bf(b.y); o.us[6] = f2bf(b.z); o.us[7] = f2bf(b.w);
  ((uint4*)dst)[i] = o.v;
}

// ---------------------------------------------------------------------------
// f32 [R][Cc] -> bf16 [Cc][R]  (validated)
// ---------------------------------------------------------------------------
__global__ __launch_bounds__(256) void transpose_convert_kernel(
    const float* __restrict__ src, short* __restrict__ dst,
    int R, int Cc)
{
  src += (size_t)blockIdx.z * R * Cc;
  dst += (size_t)blockIdx.z * (size_t)R * Cc;
  __shared__ float tile[64][65];
  int c0 = blockIdx.x * 64, r0 = blockIdx.y * 64;
  int tid = threadIdx.x;
  int tr = tid >> 4, tc = (tid & 15) * 4;
#pragma unroll
  for (int p = 0; p < 4; p++) {
    int r = p * 16 + tr;
    float4 v = *(const float4*)(src + (size_t)(r0 + r) * Cc + c0 + tc);
    tile[r][tc] = v.x; tile[r][tc + 1] = v.y; tile[r][tc + 2] = v.z; tile[r][tc + 3] = v.w;
  }
  __syncthreads();
#pragma unroll
  for (int p = 0; p < 4; p++) {
    int c = p * 16 + tr;
    union { unsigned short us[4]; ushort4 v; } o;
#pragma unroll
    for (int j = 0; j < 4; j++) o.us[j] = f2bf(tile[tc + j][c]);
    *(ushort4*)(dst + (size_t)(c0 + c) * R + r0 + tc) = o.v;
  }
}

// ---------------------------------------------------------------------------
// Simple-core MFMA GEMM, HIGH-OCCUPANCY variant (round 7): 128x128 tile,
// BK=32, 256 thr (4 waves 2x2, per-wave 64x64), double-buffered LDS 32 KB
// -> 5 blocks/CU by LDS (4-5 by VGPR). ONE __syncthreads per K-step; within
// a step: read 8 frags/wave -> issue next-step staging into buf^1 -> 16 MFMA.
// Locality decode (validated round 6): expert = flat & 7 pins expert -> XCD;
// 8-col supergroups keep the resident cohort's panels within one 4 MB L2.
// MODE 0 (mlp1): K = C_DIM; A = xbf via s2t gather; B = W1t [H][C];
//                epilogue h = gate * silu(acc) in bf16 (gate folded).
// MODE 1 (mlp2): split-K (4 chunks of 1024); A = h [cap][H]; B = W2t [C][H];
//                epilogue atomicAdd into f32 out (no gate).
// ---------------------------------------------------------------------------
template<int MODE>
__global__ __launch_bounds__(256, 4) void gemm_moe(
    const short* __restrict__ Abase, const short* __restrict__ Wt,
    const int* __restrict__ s2t, const float* __restrict__ gslot,
    const int* __restrict__ counts, void* __restrict__ outp,
    int cap, int N, int rows)
{
  __shared__ short As[2][4096];   // [buf][kb*1024 + row*8], kb in 0..3
  __shared__ short Bs[2][4096];

  // locality decode: e -> XCD, s -> supertile order within expert
  int flat = blockIdx.x;
  int e = flat & 7;
  int s = flat >> 3;
  int perGrp = rows * 8;          // tiles per 8-col supergroup
  int grp = s / perGrp;
  int loc = s - grp * perGrp;
  int r = loc >> 3;
  int c, kc;
  if (MODE == 0) { c = grp * 8 + (loc & 7); kc = 0; }
  else           { c = loc & 7;             kc = grp; }

  int cnt = counts[e];
  int row0 = r * 128;
  if (row0 >= cnt) return;        // whole block is pad slots
  int col0 = c * 128;

  int tid = threadIdx.x;
  int w = tid >> 6, l = tid & 63;
  int wr = w >> 1, wc = w & 1;
  int rowT = tid & 127, kbT = tid >> 7;   // staging: row + kb-parity (kb in {kbT, kbT+2})

  const int NS = 32;              // K-chunk 1024 both modes, BK=32

  const short *pA, *pB;
  if (MODE == 0) {
    int tok = min(s2t[(size_t)e * cap + row0 + rowT], N - 1);  // pad: harmless gather
    pA = Abase + (size_t)tok * C_DIM;
    pB = Wt + (size_t)e * (C_DIM * H_DIM) + (size_t)(col0 + rowT) * C_DIM;
  } else {
    pA = Abase + ((size_t)e * cap + row0 + rowT) * H_DIM + kc * 1024;
    pB = Wt + (size_t)e * (C_DIM * H_DIM) + (size_t)(col0 + rowT) * H_DIM + kc * 1024;
  }

  // frag read bases (shorts): [kb = l>>4][row = wq*64 + m*16 + (l&15)]
  int aBase = (l >> 4) * 1024 + (wr * 64 + (l & 15)) * 8;
  int bBase = (l >> 4) * 1024 + (wc * 64 + (l & 15)) * 8;

  f32x4 acc[4][4];
#pragma unroll
  for (int m = 0; m < 4; m++)
#pragma unroll
    for (int n = 0; n < 4; n++) acc[m][n] = 0.f;

#define STAGE(k0, buf) { \
  _Pragma("unroll") for (int j = 0; j < 2; ++j) { \
    int kb = kbT + 2 * j; \
    gload16(pA + (k0) + kb * 8, &As[buf][kb * 1024 + rowT * 8]); \
    gload16(pB + (k0) + kb * 8, &Bs[buf][kb * 1024 + rowT * 8]); \
  } }

  STAGE(0, 0);
  int cur = 0;
#pragma unroll 1
  for (int i = 0; i < NS; ++i) {
    __syncthreads();              // compiler adds vmcnt(0): buf[cur] ready
    bf16x8 af[4], bg[4];
#pragma unroll
    for (int m = 0; m < 4; m++)
      af[m] = *(const bf16x8*)&As[cur][aBase + m * 128];
#pragma unroll
    for (int n = 0; n < 4; n++)
      bg[n] = *(const bf16x8*)&Bs[cur][bBase + n * 128];
    if (i + 1 < NS) STAGE((i + 1) * 32, cur ^ 1);
#pragma unroll
    for (int m = 0; m < 4; m++)
#pragma unroll
      for (int n = 0; n < 4; n++)
        acc[m][n] = __builtin_amdgcn_mfma_f32_16x16x32_bf16(af[m], bg[n], acc[m][n], 0, 0, 0);
    cur ^= 1;
  }
#undef STAGE

  // ---- epilogue (validated C/D mapping) ----
  int orow = row0 + wr * 64 + (l >> 4) * 4;
  int ocol = col0 + wc * 64 + (l & 15);
  if (MODE == 0) {
    short* hE = (short*)outp + (size_t)e * cap * H_DIM;
#pragma unroll
    for (int m = 0; m < 4; m++)
#pragma unroll
      for (int rr = 0; rr < 4; rr++) {
        int slot = orow + m * 16 + rr;
        float g = gslot[(size_t)e * cap + slot];   // 0 for pad slots -> h = 0
        size_t rb = (size_t)slot * H_DIM + ocol;
#pragma unroll
        for (int n = 0; n < 4; n++) {
          float v = acc[m][n][rr];
          hE[rb + n * 16] = (short)f2bf(g * (v / (1.f + expf(-v))));
        }
      }
  } else {
    float* out = (float*)outp;
#pragma unroll
    for (int m = 0; m < 4; m++)
#pragma unroll
      for (int rr = 0; rr < 4; rr++) {
        int slot = orow + m * 16 + rr;
        int tok = s2t[(size_t)e * cap + slot];
        if (tok < N) {
          float* op = out + (size_t)tok * C_DIM + ocol;
#pragma unroll
          for (int n = 0; n < 4; n++)
            atomicAdd(op + n * 16, acc[m][n][rr]);
        }
      }
  }
}

extern "C" void kernel_launch(void* const* d_in, const int* in_sizes, int n_in,
                              void* d_out, int out_size, void* d_ws, size_t ws_size,
                              hipStream_t stream)
{
  const float* x     = (const float*)d_in[0];
  const float* noise = (const float*)d_in[1];
  const float* Wr    = (const float*)d_in[2];
  const float* Wn    = (const float*)d_in[3];
  const float* W1    = (const float*)d_in[4];
  const float* W2    = (const float*)d_in[5];
  float* out = (float*)d_out;

  int N = in_sizes[0] / C_DIM;                        // 8192
  int cap = (int)((double)N * 2.0 / E_NUM * 1.25);    // 2560
  int rows = cap / 128;                               // 20

  size_t off = 0;
  auto alloc = [&](size_t bytes) -> char* {
    char* r = (char*)d_ws + off;
    off += (bytes + 255) & ~(size_t)255;
    return r;
  };
  int2*   idx    = (int2*)alloc((size_t)N * sizeof(int2));
  float2* gates  = (float2*)alloc((size_t)N * sizeof(float2));
  int*    s2t    = (int*)alloc((size_t)E_NUM * cap * sizeof(int));
  float*  gslot  = (float*)alloc((size_t)E_NUM * cap * sizeof(float));
  int*    counts = (int*)alloc(E_NUM * sizeof(int));
  short*  xbf    = (short*)alloc((size_t)N * C_DIM * sizeof(short));
  short*  W1t    = (short*)alloc((size_t)E_NUM * C_DIM * H_DIM * sizeof(short));
  short*  W2t    = (short*)alloc((size_t)E_NUM * C_DIM * H_DIM * sizeof(short));
  short*  h      = (short*)alloc((size_t)E_NUM * cap * H_DIM * sizeof(short));
  (void)ws_size;

  hipMemsetAsync(d_out, 0, (size_t)out_size * sizeof(float), stream);
  router_kernel<<<N, 256, 0, stream>>>(x, noise, Wr, Wn, idx, gates, N);
  scan_kernel<<<E_NUM, 256, 0, stream>>>(idx, gates, s2t, gslot, counts, N, cap);
  convert_x_kernel<<<(N * C_DIM / 8 + 255) / 256, 256, 0, stream>>>(x, xbf, N * C_DIM / 8);
  transpose_convert_kernel<<<dim3(H_DIM / 64, C_DIM / 64, E_NUM), 256, 0, stream>>>(
      W1, W1t, C_DIM, H_DIM);
  transpose_convert_kernel<<<dim3(C_DIM / 64, H_DIM / 64, E_NUM), 256, 0, stream>>>(
      W2, W2t, H_DIM, C_DIM);

  // mlp1: 8 experts x 4 col-supergroups x (rows*8) = 5120 blocks
  gemm_moe<0><<<dim3(E_NUM * (H_DIM / 128 / 8) * (rows * 8)), 256, 0, stream>>>(
      xbf, W1t, s2t, gslot, counts, h, cap, N, rows);
  // mlp2: 8 experts x 4 K-chunks x (rows*8) = 5120 blocks
  gemm_moe<1><<<dim3(E_NUM * 4 * (rows * 8)), 256, 0, stream>>>(
      h, W2t, s2t, gslot, counts, out, cap, N, rows);
}

// Round 8
// 860.090 us; speedup vs baseline: 1.0941x; 1.0314x over previous
//
#include <hip/hip_runtime.h>
#include <hip/hip_bf16.h>
#include <math.h>

#define C_DIM 1024
#define H_DIM 4096
#define E_NUM 8

typedef __bf16 bf16x8 __attribute__((ext_vector_type(8)));
typedef float f32x4 __attribute__((ext_vector_type(4)));

__device__ __forceinline__ unsigned short f2bf(float f) {
  union { float f; unsigned u; } v; v.f = f;
  unsigned r = v.u + 0x7FFFu + ((v.u >> 16) & 1u);   // round-to-nearest-even
  return (unsigned short)(r >> 16);
}

__device__ __forceinline__ void gload16(const short* g, short* l) {
  __builtin_amdgcn_global_load_lds(
      (const __attribute__((address_space(1))) unsigned int*)g,
      (__attribute__((address_space(3))) unsigned int*)l, 16, 0, 0);
}

// ---------------------------------------------------------------------------
// Router (validated rounds 1-7)
// ---------------------------------------------------------------------------
__global__ __launch_bounds__(256) void router_kernel(
    const float* __restrict__ x, const float* __restrict__ noise,
    const float* __restrict__ Wr, const float* __restrict__ Wn,
    int2* __restrict__ idx_out, float2* __restrict__ gate_out, int N)
{
  int t = blockIdx.x;
  int tid = threadIdx.x;
  const float* xrow = x + (size_t)t * C_DIM;
  float accR[E_NUM], accN[E_NUM];
#pragma unroll
  for (int e = 0; e < E_NUM; e++) { accR[e] = 0.f; accN[e] = 0.f; }
  for (int c = tid; c < C_DIM; c += 256) {
    float xv = xrow[c];
    const float* wr = Wr + (size_t)c * E_NUM;
    const float* wn = Wn + (size_t)c * E_NUM;
#pragma unroll
    for (int e = 0; e < E_NUM; e++) {
      accR[e] = fmaf(xv, wr[e], accR[e]);
      accN[e] = fmaf(xv, wn[e], accN[e]);
    }
  }
#pragma unroll
  for (int e = 0; e < E_NUM; e++) {
    for (int off = 32; off > 0; off >>= 1) {
      accR[e] += __shfl_down(accR[e], off, 64);
      accN[e] += __shfl_down(accN[e], off, 64);
    }
  }
  __shared__ float red[4][2 * E_NUM];
  int lane = tid & 63, wave = tid >> 6;
  if (lane == 0) {
#pragma unroll
    for (int e = 0; e < E_NUM; e++) { red[wave][e] = accR[e]; red[wave][E_NUM + e] = accN[e]; }
  }
  __syncthreads();
  if (tid == 0) {
    float ns[E_NUM];
#pragma unroll
    for (int e = 0; e < E_NUM; e++) {
      float lg = red[0][e] + red[1][e] + red[2][e] + red[3][e];
      float nl = red[0][E_NUM + e] + red[1][E_NUM + e] + red[2][E_NUM + e] + red[3][E_NUM + e];
      float sp = fmaxf(nl, 0.f) + log1pf(expf(-fabsf(nl)));
      ns[e] = lg + noise[(size_t)t * E_NUM + e] * sp;
    }
    int i1 = 0; float m1 = ns[0];
    int i2 = -1; float m2 = -INFINITY;
#pragma unroll
    for (int e = 1; e < E_NUM; e++) {
      float v = ns[e];
      if (v > m1) { m2 = m1; i2 = i1; m1 = v; i1 = e; }
      else if (v > m2) { m2 = v; i2 = e; }
    }
    float e2 = expf(m2 - m1);
    float s = 1.f + e2;
    gate_out[t] = make_float2(1.f / s, e2 / s);
    idx_out[t] = make_int2(i1, i2);
  }
}

// ---------------------------------------------------------------------------
// Capacity scan (validated) + per-expert kept count
// ---------------------------------------------------------------------------
__global__ __launch_bounds__(256) void scan_kernel(
    const int2* __restrict__ idx, const float2* __restrict__ gates,
    int* __restrict__ s2t, float* __restrict__ gslot, int* __restrict__ counts,
    int N, int cap)
{
  int e = blockIdx.x;
  int tid = threadIdx.x;
  for (int s = tid; s < cap; s += 256) { s2t[(size_t)e * cap + s] = N; gslot[(size_t)e * cap + s] = 0.f; }
  __syncthreads();
  __shared__ int wtot[4];
  int lane = tid & 63, wave = tid >> 6;
  int running = 0;
  for (int base = 0; base < N; base += 256) {
    int t = base + tid;
    int2 ix = idx[t];
    bool flag = (ix.x == e) || (ix.y == e);
    unsigned long long m = __ballot(flag);
    int rank = __popcll(m & ((1ull << lane) - 1ull));
    if (lane == 0) wtot[wave] = __popcll(m);
    __syncthreads();
    int woff = 0;
    for (int w = 0; w < wave; w++) woff += wtot[w];
    int slot = running + woff + rank;
    if (flag && slot < cap) {
      s2t[(size_t)e * cap + slot] = t;
      gslot[(size_t)e * cap + slot] = (ix.x == e) ? gates[t].x : gates[t].y;
    }
    running += wtot[0] + wtot[1] + wtot[2] + wtot[3];
    __syncthreads();
  }
  if (tid == 0) counts[e] = min(running, cap);
}

// ---------------------------------------------------------------------------
// f32 -> bf16, 8 elems/thread (validated)
// ---------------------------------------------------------------------------
__global__ __launch_bounds__(256) void convert_x_kernel(
    const float* __restrict__ src, short* __restrict__ dst, int n8)
{
  int i = blockIdx.x * 256 + threadIdx.x;
  if (i >= n8) return;
  const float4* s = (const float4*)src + (size_t)i * 2;
  float4 a = s[0], b = s[1];
  union { unsigned short us[8]; uint4 v; } o;
  o.us[0] = f2bf(a.x); o.us[1] = f2bf(a.y); o.us[2] = f2bf(a.z); o.us[3] = f2bf(a.w);
  o.us[4] = f2bf(b.x); o.us[5] = f2bf(b.y); o.us[6] = f2bf(b.z); o.us[7] = f2bf(b.w);
  ((uint4*)dst)[i] = o.v;
}

// ---------------------------------------------------------------------------
// f32 [R][Cc] -> bf16 [Cc][R]  (validated)
// ---------------------------------------------------------------------------
__global__ __launch_bounds__(256) void transpose_convert_kernel(
    const float* __restrict__ src, short* __restrict__ dst,
    int R, int Cc)
{
  src += (size_t)blockIdx.z * R * Cc;
  dst += (size_t)blockIdx.z * (size_t)R * Cc;
  __shared__ float tile[64][65];
  int c0 = blockIdx.x * 64, r0 = blockIdx.y * 64;
  int tid = threadIdx.x;
  int tr = tid >> 4, tc = (tid & 15) * 4;
#pragma unroll
  for (int p = 0; p < 4; p++) {
    int r = p * 16 + tr;
    float4 v = *(const float4*)(src + (size_t)(r0 + r) * Cc + c0 + tc);
    tile[r][tc] = v.x; tile[r][tc + 1] = v.y; tile[r][tc + 2] = v.z; tile[r][tc + 3] = v.w;
  }
  __syncthreads();
#pragma unroll
  for (int p = 0; p < 4; p++) {
    int c = p * 16 + tr;
    union { unsigned short us[4]; ushort4 v; } o;
#pragma unroll
    for (int j = 0; j < 4; j++) o.us[j] = f2bf(tile[tc + j][c]);
    *(ushort4*)(dst + (size_t)(c0 + c) * R + r0 + tc) = o.v;
  }
}

// ---------------------------------------------------------------------------
// Round 8: R7's validated loop structure scaled to BM=BN=256 (halves staged
// bytes/FLOP; we are fabric-BW-bound at ~6.5 TB/s into the CUs).
// 512 thr = 8 waves (2M x 4N), per-wave 128x64 output, acc[8][4].
// BK=32, double-buffered LDS 2x(16+16) KB = 64 KB. ONE __syncthreads per
// K-step; within a step: read 12 frags/wave -> issue next-step staging into
// buf^1 -> 32 MFMA. Compiler's vmcnt(0)+lgkmcnt(0) at the barrier is exactly
// the required wait (R5/R7-proven to sustain ~6.5 TB/s staging).
// LDS per buffer: [kb=4][row=256][8] bf16, lane-linear staging, 0-conflict
// b128 reads (validated geometry, rows 2-7).
// MODE 0 (mlp1): K=C_DIM; A = xbf via s2t gather; B = W1t [H][C];
//                epilogue h = gate * silu(acc) in bf16 (gate folded).
// MODE 1 (mlp2): split-K (4 chunks of 1024); A = h [cap][H]; B = W2t [C][H];
//                epilogue atomicAdd into f32 out (no gate).
// ---------------------------------------------------------------------------
template<int MODE>
__global__ __launch_bounds__(512, 2) void gemm_moe(
    const short* __restrict__ Abase, const short* __restrict__ Wt,
    const int* __restrict__ s2t, const float* __restrict__ gslot,
    const int* __restrict__ counts, void* __restrict__ outp,
    int cap, int N, int rows)
{
  __shared__ short As[2][8192];   // [buf][kb*2048 + row*8], kb 0..3, row 0..255
  __shared__ short Bs[2][8192];

  // decode: e -> XCD pin (flat & 7); r fastest within expert
  int flat = blockIdx.x;
  int e = flat & 7;
  int s = flat >> 3;
  int r = s % rows;
  int t = s / rows;
  int c, kc;
  if (MODE == 0) { c = t; kc = 0; }
  else           { c = t & 3; kc = t >> 2; }

  int cnt = counts[e];
  int row0 = r * 256;
  if (row0 >= cnt) return;        // whole block is pad slots
  int col0 = c * 256;

  int tid = threadIdx.x;
  int w = tid >> 6, l = tid & 63;
  int wr = w >> 2, wc = w & 3;            // 2M x 4N wave grid
  int rowT = tid & 255, kbT = tid >> 8;   // staging: row 0..255, kb parity 0/1

  const int NS = 32;              // K-chunk 1024 both modes, BK=32

  const short *pA, *pB;
  if (MODE == 0) {
    int tok = min(s2t[(size_t)e * cap + row0 + rowT], N - 1);  // pad: harmless gather
    pA = Abase + (size_t)tok * C_DIM;
    pB = Wt + (size_t)e * (C_DIM * H_DIM) + (size_t)(col0 + rowT) * C_DIM;
  } else {
    pA = Abase + ((size_t)e * cap + row0 + rowT) * H_DIM + kc * 1024;
    pB = Wt + (size_t)e * (C_DIM * H_DIM) + (size_t)(col0 + rowT) * H_DIM + kc * 1024;
  }

  // frag read bases (shorts): [kb = l>>4][row]: A row = wr*128 + m*16 + (l&15),
  // B col = wc*64 + n*16 + (l&15)
  int aBase = (l >> 4) * 2048 + (wr * 128 + (l & 15)) * 8;
  int bBase = (l >> 4) * 2048 + (wc * 64 + (l & 15)) * 8;

  f32x4 acc[8][4];
#pragma unroll
  for (int m = 0; m < 8; m++)
#pragma unroll
    for (int n = 0; n < 4; n++) acc[m][n] = 0.f;

#define STAGE(k0, buf) { \
  gload16(pA + (k0) + kbT * 8,       &As[buf][kbT * 2048 + rowT * 8]); \
  gload16(pA + (k0) + (kbT + 2) * 8, &As[buf][(kbT + 2) * 2048 + rowT * 8]); \
  gload16(pB + (k0) + kbT * 8,       &Bs[buf][kbT * 2048 + rowT * 8]); \
  gload16(pB + (k0) + (kbT + 2) * 8, &Bs[buf][(kbT + 2) * 2048 + rowT * 8]); }

  STAGE(0, 0);
  int cur = 0;
#pragma unroll 1
  for (int i = 0; i < NS; ++i) {
    __syncthreads();              // compiler adds vmcnt(0): buf[cur] ready
    bf16x8 af[8], bg[4];
#pragma unroll
    for (int m = 0; m < 8; m++)
      af[m] = *(const bf16x8*)&As[cur][aBase + m * 128];
#pragma unroll
    for (int n = 0; n < 4; n++)
      bg[n] = *(const bf16x8*)&Bs[cur][bBase + n * 128];
    if (i + 1 < NS) STAGE((i + 1) * 32, cur ^ 1);
#pragma unroll
    for (int m = 0; m < 8; m++)
#pragma unroll
      for (int n = 0; n < 4; n++)
        acc[m][n] = __builtin_amdgcn_mfma_f32_16x16x32_bf16(af[m], bg[n], acc[m][n], 0, 0, 0);
    cur ^= 1;
  }
#undef STAGE

  // ---- epilogue (8-wave mapping validated rounds 3-4) ----
  int orow = row0 + wr * 128 + (l >> 4) * 4;
  int ocol = col0 + wc * 64 + (l & 15);
  if (MODE == 0) {
    short* hE = (short*)outp + (size_t)e * cap * H_DIM;
#pragma unroll
    for (int m = 0; m < 8; m++)
#pragma unroll
      for (int rr = 0; rr < 4; rr++) {
        int slot = orow + m * 16 + rr;
        float g = gslot[(size_t)e * cap + slot];   // 0 for pad slots -> h = 0
        size_t rb = (size_t)slot * H_DIM + ocol;
#pragma unroll
        for (int n = 0; n < 4; n++) {
          float v = acc[m][n][rr];
          hE[rb + n * 16] = (short)f2bf(g * (v / (1.f + expf(-v))));
        }
      }
  } else {
    float* out = (float*)outp;
#pragma unroll
    for (int m = 0; m < 8; m++)
#pragma unroll
      for (int rr = 0; rr < 4; rr++) {
        int slot = orow + m * 16 + rr;
        int tok = s2t[(size_t)e * cap + slot];
        if (tok < N) {
          float* op = out + (size_t)tok * C_DIM + ocol;
#pragma unroll
          for (int n = 0; n < 4; n++)
            atomicAdd(op + n * 16, acc[m][n][rr]);
        }
      }
  }
}

extern "C" void kernel_launch(void* const* d_in, const int* in_sizes, int n_in,
                              void* d_out, int out_size, void* d_ws, size_t ws_size,
                              hipStream_t stream)
{
  const float* x     = (const float*)d_in[0];
  const float* noise = (const float*)d_in[1];
  const float* Wr    = (const float*)d_in[2];
  const float* Wn    = (const float*)d_in[3];
  const float* W1    = (const float*)d_in[4];
  const float* W2    = (const float*)d_in[5];
  float* out = (float*)d_out;

  int N = in_sizes[0] / C_DIM;                        // 8192
  int cap = (int)((double)N * 2.0 / E_NUM * 1.25);    // 2560
  int rows = cap / 256;                               // 10

  size_t off = 0;
  auto alloc = [&](size_t bytes) -> char* {
    char* r = (char*)d_ws + off;
    off += (bytes + 255) & ~(size_t)255;
    return r;
  };
  int2*   idx    = (int2*)alloc((size_t)N * sizeof(int2));
  float2* gates  = (float2*)alloc((size_t)N * sizeof(float2));
  int*    s2t    = (int*)alloc((size_t)E_NUM * cap * sizeof(int));
  float*  gslot  = (float*)alloc((size_t)E_NUM * cap * sizeof(float));
  int*    counts = (int*)alloc(E_NUM * sizeof(int));
  short*  xbf    = (short*)alloc((size_t)N * C_DIM * sizeof(short));
  short*  W1t    = (short*)alloc((size_t)E_NUM * C_DIM * H_DIM * sizeof(short));
  short*  W2t    = (short*)alloc((size_t)E_NUM * C_DIM * H_DIM * sizeof(short));
  short*  h      = (short*)alloc((size_t)E_NUM * cap * H_DIM * sizeof(short));
  (void)ws_size;

  hipMemsetAsync(d_out, 0, (size_t)out_size * sizeof(float), stream);
  router_kernel<<<N, 256, 0, stream>>>(x, noise, Wr, Wn, idx, gates, N);
  scan_kernel<<<E_NUM, 256, 0, stream>>>(idx, gates, s2t, gslot, counts, N, cap);
  convert_x_kernel<<<(N * C_DIM / 8 + 255) / 256, 256, 0, stream>>>(x, xbf, N * C_DIM / 8);
  transpose_convert_kernel<<<dim3(H_DIM / 64, C_DIM / 64, E_NUM), 256, 0, stream>>>(
      W1, W1t, C_DIM, H_DIM);
  transpose_convert_kernel<<<dim3(C_DIM / 64, H_DIM / 64, E_NUM), 256, 0, stream>>>(
      W2, W2t, H_DIM, C_DIM);

  // mlp1: 8 experts x (10 rows x 16 cols) = 1280 blocks of 512 thr
  gemm_moe<0><<<dim3(E_NUM * rows * (H_DIM / 256)), 512, 0, stream>>>(
      xbf, W1t, s2t, gslot, counts, h, cap, N, rows);
  // mlp2: 8 experts x (10 rows x 4 cols x 4 kchunks) = 1280 blocks
  gemm_moe<1><<<dim3(E_NUM * rows * 4 * 4), 512, 0, stream>>>(
      h, W2t, s2t, gslot, counts, out, cap, N, rows);
}

// Round 9
// 810.377 us; speedup vs baseline: 1.1612x; 1.0613x over previous
//
#include <hip/hip_runtime.h>
#include <hip/hip_bf16.h>
#include <math.h>

#define C_DIM 1024
#define H_DIM 4096
#define E_NUM 8

typedef __bf16 bf16x8 __attribute__((ext_vector_type(8)));
typedef float f32x4 __attribute__((ext_vector_type(4)));
typedef unsigned u32x4 __attribute__((ext_vector_type(4)));

__device__ __forceinline__ unsigned short f2bf(float f) {
  union { float f; unsigned u; } v; v.f = f;
  unsigned r = v.u + 0x7FFFu + ((v.u >> 16) & 1u);   // round-to-nearest-even
  return (unsigned short)(r >> 16);
}

__device__ __forceinline__ void gload16(const short* g, short* l) {
  __builtin_amdgcn_global_load_lds(
      (const __attribute__((address_space(1))) unsigned int*)g,
      (__attribute__((address_space(3))) unsigned int*)l, 16, 0, 0);
}

__device__ __forceinline__ f32x4 mfma16(u32x4 a, u32x4 b, f32x4 c) {
  return __builtin_amdgcn_mfma_f32_16x16x32_bf16(
      __builtin_bit_cast(bf16x8, a), __builtin_bit_cast(bf16x8, b), c, 0, 0, 0);
}

// asm ds_read_b128: invisible to the compiler LDS-DMA hazard pass (which
// otherwise inserts vmcnt(0) before LDS reads aliasing global_load_lds dests).
#define DSR(v, a, imm) asm volatile("ds_read_b128 %0, %1 offset:" #imm : "=v"(v) : "v"(a))
#define LGKM0 { asm volatile("s_waitcnt lgkmcnt(0)" ::: "memory"); __builtin_amdgcn_sched_barrier(0); }
#define VMW(n) asm volatile("s_waitcnt vmcnt(" #n ")" ::: "memory")
#define LDS_U32(p) ((unsigned)(size_t)(__attribute__((address_space(3))) short*)(p))

// ---------------------------------------------------------------------------
// Router (validated rounds 1-8)
// ---------------------------------------------------------------------------
__global__ __launch_bounds__(256) void router_kernel(
    const float* __restrict__ x, const float* __restrict__ noise,
    const float* __restrict__ Wr, const float* __restrict__ Wn,
    int2* __restrict__ idx_out, float2* __restrict__ gate_out, int N)
{
  int t = blockIdx.x;
  int tid = threadIdx.x;
  const float* xrow = x + (size_t)t * C_DIM;
  float accR[E_NUM], accN[E_NUM];
#pragma unroll
  for (int e = 0; e < E_NUM; e++) { accR[e] = 0.f; accN[e] = 0.f; }
  for (int c = tid; c < C_DIM; c += 256) {
    float xv = xrow[c];
    const float* wr = Wr + (size_t)c * E_NUM;
    const float* wn = Wn + (size_t)c * E_NUM;
#pragma unroll
    for (int e = 0; e < E_NUM; e++) {
      accR[e] = fmaf(xv, wr[e], accR[e]);
      accN[e] = fmaf(xv, wn[e], accN[e]);
    }
  }
#pragma unroll
  for (int e = 0; e < E_NUM; e++) {
    for (int off = 32; off > 0; off >>= 1) {
      accR[e] += __shfl_down(accR[e], off, 64);
      accN[e] += __shfl_down(accN[e], off, 64);
    }
  }
  __shared__ float red[4][2 * E_NUM];
  int lane = tid & 63, wave = tid >> 6;
  if (lane == 0) {
#pragma unroll
    for (int e = 0; e < E_NUM; e++) { red[wave][e] = accR[e]; red[wave][E_NUM + e] = accN[e]; }
  }
  __syncthreads();
  if (tid == 0) {
    float ns[E_NUM];
#pragma unroll
    for (int e = 0; e < E_NUM; e++) {
      float lg = red[0][e] + red[1][e] + red[2][e] + red[3][e];
      float nl = red[0][E_NUM + e] + red[1][E_NUM + e] + red[2][E_NUM + e] + red[3][E_NUM + e];
      float sp = fmaxf(nl, 0.f) + log1pf(expf(-fabsf(nl)));
      ns[e] = lg + noise[(size_t)t * E_NUM + e] * sp;
    }
    int i1 = 0; float m1 = ns[0];
    int i2 = -1; float m2 = -INFINITY;
#pragma unroll
    for (int e = 1; e < E_NUM; e++) {
      float v = ns[e];
      if (v > m1) { m2 = m1; i2 = i1; m1 = v; i1 = e; }
      else if (v > m2) { m2 = v; i2 = e; }
    }
    float e2 = expf(m2 - m1);
    float s = 1.f + e2;
    gate_out[t] = make_float2(1.f / s, e2 / s);
    idx_out[t] = make_int2(i1, i2);
  }
}

// ---------------------------------------------------------------------------
// Capacity scan (validated) + per-expert kept count
// ---------------------------------------------------------------------------
__global__ __launch_bounds__(256) void scan_kernel(
    const int2* __restrict__ idx, const float2* __restrict__ gates,
    int* __restrict__ s2t, float* __restrict__ gslot, int* __restrict__ counts,
    int N, int cap)
{
  int e = blockIdx.x;
  int tid = threadIdx.x;
  for (int s = tid; s < cap; s += 256) { s2t[(size_t)e * cap + s] = N; gslot[(size_t)e * cap + s] = 0.f; }
  __syncthreads();
  __shared__ int wtot[4];
  int lane = tid & 63, wave = tid >> 6;
  int running = 0;
  for (int base = 0; base < N; base += 256) {
    int t = base + tid;
    int2 ix = idx[t];
    bool flag = (ix.x == e) || (ix.y == e);
    unsigned long long m = __ballot(flag);
    int rank = __popcll(m & ((1ull << lane) - 1ull));
    if (lane == 0) wtot[wave] = __popcll(m);
    __syncthreads();
    int woff = 0;
    for (int w = 0; w < wave; w++) woff += wtot[w];
    int slot = running + woff + rank;
    if (flag && slot < cap) {
      s2t[(size_t)e * cap + slot] = t;
      gslot[(size_t)e * cap + slot] = (ix.x == e) ? gates[t].x : gates[t].y;
    }
    running += wtot[0] + wtot[1] + wtot[2] + wtot[3];
    __syncthreads();
  }
  if (tid == 0) counts[e] = min(running, cap);
}

// ---------------------------------------------------------------------------
// f32 -> bf16, 8 elems/thread (validated)
// ---------------------------------------------------------------------------
__global__ __launch_bounds__(256) void convert_x_kernel(
    const float* __restrict__ src, short* __restrict__ dst, int n8)
{
  int i = blockIdx.x * 256 + threadIdx.x;
  if (i >= n8) return;
  const float4* s = (const float4*)src + (size_t)i * 2;
  float4 a = s[0], b = s[1];
  union { unsigned short us[8]; uint4 v; } o;
  o.us[0] = f2bf(a.x); o.us[1] = f2bf(a.y); o.us[2] = f2bf(a.z); o.us[3] = f2bf(a.w);
  o.us[4] = f2bf(b.x); o.us[5] = f2bf(b.y); o.us[6] = f2bf(b.z); o.us[7] = f2bf(b.w);
  ((uint4*)dst)[i] = o.v;
}

// ---------------------------------------------------------------------------
// f32 [R][Cc] -> bf16 [Cc][R]  (validated)
// ---------------------------------------------------------------------------
__global__ __launch_bounds__(256) void transpose_convert_kernel(
    const float* __restrict__ src, short* __restrict__ dst,
    int R, int Cc)
{
  src += (size_t)blockIdx.z * R * Cc;
  dst += (size_t)blockIdx.z * (size_t)R * Cc;
  __shared__ float tile[64][65];
  int c0 = blockIdx.x * 64, r0 = blockIdx.y * 64;
  int tid = threadIdx.x;
  int tr = tid >> 4, tc = (tid & 15) * 4;
#pragma unroll
  for (int p = 0; p < 4; p++) {
    int r = p * 16 + tr;
    float4 v = *(const float4*)(src + (size_t)(r0 + r) * Cc + c0 + tc);
    tile[r][tc] = v.x; tile[r][tc + 1] = v.y; tile[r][tc + 2] = v.z; tile[r][tc + 3] = v.w;
  }
  __syncthreads();
#pragma unroll
  for (int p = 0; p < 4; p++) {
    int c = p * 16 + tr;
    union { unsigned short us[4]; ushort4 v; } o;
#pragma unroll
    for (int j = 0; j < 4; j++) o.us[j] = f2bf(tile[tc + j][c]);
    *(ushort4*)(dst + (size_t)(c0 + c) * R + r0 + tc) = o.v;
  }
}

// ---------------------------------------------------------------------------
// Round 9: R8 geometry (BM=BN=256, BK=32, 512 thr = 8 waves 2Mx4N, per-wave
// 128x64, acc[8][4], [kb][row][8] conflict-free LDS) with a DEPTH-2 pipeline:
// 3 LDS buffers (96 KB), ONE raw s_barrier + counted vmcnt(4) per K-step,
// asm ds_read_b128 (hazard-pass-blind). Loads for step i are issued at step
// i-2 -> ~2 steps (>900 cyc) of latency slack, never drained mid-loop.
// vmcnt counts INSTRUCTIONS: STAGE = 4 global_load_lds per thread.
//   prologue: stage steps 0,1 (8 outstanding)
//   step i: vmcnt(4) [step-i's 4 retired; in-order completion makes this
//           exact] -> s_barrier -> 12 asm ds_read -> stage step i+2 ->
//           lgkmcnt(0)+sched_barrier -> setprio(1) 32 MFMA setprio(0).
// Safety: ds_reads retire (lgkmcnt 0) before MFMA, so before any wave reaches
// the next barrier -- the restage of a just-read buffer can never race.
// MODE 0 (mlp1): A = xbf via s2t gather, B = W1t [H][C]; h = gate*silu (bf16).
// MODE 1 (mlp2): split-K (4 chunks); A = h [cap][H]; B = W2t [C][H]; atomicAdd.
// ---------------------------------------------------------------------------
template<int MODE>
__global__ __launch_bounds__(512, 2) void gemm_moe(
    const short* __restrict__ Abase, const short* __restrict__ Wt,
    const int* __restrict__ s2t, const float* __restrict__ gslot,
    const int* __restrict__ counts, void* __restrict__ outp,
    int cap, int N, int rows)
{
  __shared__ short As[3][8192];   // [buf][kb*2048 + row*8], 16 KB per buffer
  __shared__ short Bs[3][8192];

  // decode (validated R8): e -> XCD pin; r fastest within expert
  int flat = blockIdx.x;
  int e = flat & 7;
  int s = flat >> 3;
  int r = s % rows;
  int t = s / rows;
  int c, kc;
  if (MODE == 0) { c = t; kc = 0; }
  else           { c = t & 3; kc = t >> 2; }

  int cnt = counts[e];
  int row0 = r * 256;
  if (row0 >= cnt) return;        // whole block is pad slots (no barriers yet)
  int col0 = c * 256;

  int tid = threadIdx.x;
  int w = tid >> 6, l = tid & 63;
  int wr = w >> 2, wc = w & 3;            // 2M x 4N wave grid
  int rowT = tid & 255, kbT = tid >> 8;   // staging: row 0..255, kb parity 0/1

  const int NS = 32;              // K-chunk 1024 both modes, BK=32

  const short *pA, *pB;
  if (MODE == 0) {
    int tok = min(s2t[(size_t)e * cap + row0 + rowT], N - 1);  // pad: harmless gather
    pA = Abase + (size_t)tok * C_DIM;
    pB = Wt + (size_t)e * (C_DIM * H_DIM) + (size_t)(col0 + rowT) * C_DIM;
  } else {
    pA = Abase + ((size_t)e * cap + row0 + rowT) * H_DIM + kc * 1024;
    pB = Wt + (size_t)e * (C_DIM * H_DIM) + (size_t)(col0 + rowT) * H_DIM + kc * 1024;
  }

  // asm ds_read byte bases within buffer 0 (add bufR for rotation):
  // A row = wr*128 + m*16 + (l&15), kb = l>>4; stride m -> 256 B
  unsigned aB = LDS_U32(As) + (unsigned)((l >> 4) * 4096 + (wr * 128 + (l & 15)) * 16);
  unsigned bB = LDS_U32(Bs) + (unsigned)((l >> 4) * 4096 + (wc * 64 + (l & 15)) * 16);

  f32x4 acc[8][4];
#pragma unroll
  for (int m = 0; m < 8; m++)
#pragma unroll
    for (int n = 0; n < 4; n++) acc[m][n] = 0.f;

#define STAGE(k0, buf) { \
  gload16(pA + (k0) + kbT * 8,       &As[buf][kbT * 2048 + rowT * 8]); \
  gload16(pA + (k0) + (kbT + 2) * 8, &As[buf][(kbT + 2) * 2048 + rowT * 8]); \
  gload16(pB + (k0) + kbT * 8,       &Bs[buf][kbT * 2048 + rowT * 8]); \
  gload16(pB + (k0) + (kbT + 2) * 8, &Bs[buf][(kbT + 2) * 2048 + rowT * 8]); }

  // prologue: steps 0 and 1 in flight (8 vmem instr/thread)
  STAGE(0, 0);
  STAGE(32, 1);

  unsigned bufR = 0;              // byte offset of current read buffer
  int bufS = 2;                   // index of next stage buffer
#pragma unroll 1
  for (int i = 0; i < NS; ++i) {
    if (i == NS - 1) { VMW(0); } else { VMW(4); }
    __builtin_amdgcn_s_barrier();
    __builtin_amdgcn_sched_barrier(0);

    u32x4 af[8], bg[4];
    unsigned aA = aB + bufR, bA = bB + bufR;
    DSR(af[0], aA, 0);    DSR(af[1], aA, 256);  DSR(af[2], aA, 512);  DSR(af[3], aA, 768);
    DSR(af[4], aA, 1024); DSR(af[5], aA, 1280); DSR(af[6], aA, 1536); DSR(af[7], aA, 1792);
    DSR(bg[0], bA, 0);    DSR(bg[1], bA, 256);  DSR(bg[2], bA, 512);  DSR(bg[3], bA, 768);

    if (i + 2 < NS) {
      STAGE((i + 2) * 32, bufS);
      bufS = (bufS == 2) ? 0 : bufS + 1;
    }

    LGKM0;
    __builtin_amdgcn_s_setprio(1);
#pragma unroll
    for (int m = 0; m < 8; m++)
#pragma unroll
      for (int n = 0; n < 4; n++)
        acc[m][n] = mfma16(af[m], bg[n], acc[m][n]);
    __builtin_amdgcn_s_setprio(0);

    bufR = (bufR == 32768u) ? 0u : bufR + 16384u;
  }
#undef STAGE

  // ---- epilogue (validated R8) ----
  int orow = row0 + wr * 128 + (l >> 4) * 4;
  int ocol = col0 + wc * 64 + (l & 15);
  if (MODE == 0) {
    short* hE = (short*)outp + (size_t)e * cap * H_DIM;
#pragma unroll
    for (int m = 0; m < 8; m++)
#pragma unroll
      for (int rr = 0; rr < 4; rr++) {
        int slot = orow + m * 16 + rr;
        float g = gslot[(size_t)e * cap + slot];   // 0 for pad slots -> h = 0
        size_t rb = (size_t)slot * H_DIM + ocol;
#pragma unroll
        for (int n = 0; n < 4; n++) {
          float v = acc[m][n][rr];
          hE[rb + n * 16] = (short)f2bf(g * (v / (1.f + expf(-v))));
        }
      }
  } else {
    float* out = (float*)outp;
#pragma unroll
    for (int m = 0; m < 8; m++)
#pragma unroll
      for (int rr = 0; rr < 4; rr++) {
        int slot = orow + m * 16 + rr;
        int tok = s2t[(size_t)e * cap + slot];
        if (tok < N) {
          float* op = out + (size_t)tok * C_DIM + ocol;
#pragma unroll
          for (int n = 0; n < 4; n++)
            atomicAdd(op + n * 16, acc[m][n][rr]);
        }
      }
  }
}

extern "C" void kernel_launch(void* const* d_in, const int* in_sizes, int n_in,
                              void* d_out, int out_size, void* d_ws, size_t ws_size,
                              hipStream_t stream)
{
  const float* x     = (const float*)d_in[0];
  const float* noise = (const float*)d_in[1];
  const float* Wr    = (const float*)d_in[2];
  const float* Wn    = (const float*)d_in[3];
  const float* W1    = (const float*)d_in[4];
  const float* W2    = (const float*)d_in[5];
  float* out = (float*)d_out;

  int N = in_sizes[0] / C_DIM;                        // 8192
  int cap = (int)((double)N * 2.0 / E_NUM * 1.25);    // 2560
  int rows = cap / 256;                               // 10

  size_t off = 0;
  auto alloc = [&](size_t bytes) -> char* {
    char* r = (char*)d_ws + off;
    off += (bytes + 255) & ~(size_t)255;
    return r;
  };
  int2*   idx    = (int2*)alloc((size_t)N * sizeof(int2));
  float2* gates  = (float2*)alloc((size_t)N * sizeof(float2));
  int*    s2t    = (int*)alloc((size_t)E_NUM * cap * sizeof(int));
  float*  gslot  = (float*)alloc((size_t)E_NUM * cap * sizeof(float));
  int*    counts = (int*)alloc(E_NUM * sizeof(int));
  short*  xbf    = (short*)alloc((size_t)N * C_DIM * sizeof(short));
  short*  W1t    = (short*)alloc((size_t)E_NUM * C_DIM * H_DIM * sizeof(short));
  short*  W2t    = (short*)alloc((size_t)E_NUM * C_DIM * H_DIM * sizeof(short));
  short*  h      = (short*)alloc((size_t)E_NUM * cap * H_DIM * sizeof(short));
  (void)ws_size;

  hipMemsetAsync(d_out, 0, (size_t)out_size * sizeof(float), stream);
  router_kernel<<<N, 256, 0, stream>>>(x, noise, Wr, Wn, idx, gates, N);
  scan_kernel<<<E_NUM, 256, 0, stream>>>(idx, gates, s2t, gslot, counts, N, cap);
  convert_x_kernel<<<(N * C_DIM / 8 + 255) / 256, 256, 0, stream>>>(x, xbf, N * C_DIM / 8);
  transpose_convert_kernel<<<dim3(H_DIM / 64, C_DIM / 64, E_NUM), 256, 0, stream>>>(
      W1, W1t, C_DIM, H_DIM);
  transpose_convert_kernel<<<dim3(C_DIM / 64, H_DIM / 64, E_NUM), 256, 0, stream>>>(
      W2, W2t, H_DIM, C_DIM);

  // mlp1: 8 experts x (10 rows x 16 cols) = 1280 blocks of 512 thr
  gemm_moe<0><<<dim3(E_NUM * rows * (H_DIM / 256)), 512, 0, stream>>>(
      xbf, W1t, s2t, gslot, counts, h, cap, N, rows);
  // mlp2: 8 experts x (10 rows x 4 cols x 4 kchunks) = 1280 blocks
  gemm_moe<1><<<dim3(E_NUM * rows * 4 * 4), 512, 0, stream>>>(
      h, W2t, s2t, gslot, counts, out, cap, N, rows);
}